// Round 1
// baseline (210.331 us; speedup 1.0000x reference)
//
#include <hip/hip_runtime.h>

// Problem constants (fixed by setup_inputs)
#define BB   4        // batch
#define SS   2048     // sequence
#define DD   768      // hidden
#define NN   4096     // spans
#define PW   20       // pos/width table width
#define CH   64       // cumsum chunk length
#define NCH  32       // SS / CH
#define ROW  2364     // output row length: 3*768 + 3*20

// Kernel 1: per-chunk partial sums along S.  grid (3, NCH, BB), block 256.
__global__ void partial_kernel(const float* __restrict__ x, float* __restrict__ partial) {
    int d = blockIdx.x * 256 + threadIdx.x;   // 0..767
    int c = blockIdx.y;
    int b = blockIdx.z;
    const float* xp = x + ((size_t)(b * SS + c * CH)) * DD + d;
    float s = 0.f;
#pragma unroll
    for (int i = 0; i < CH; ++i) s += xp[(size_t)i * DD];
    partial[(b * NCH + c) * DD + d] = s;
}

// Kernel 2: exclusive prefix over the NCH chunk sums of each (b,d) column.
// grid 12 blocks x 256 = 3072 threads = BB*DD.
__global__ void prefix_kernel(float* __restrict__ partial) {
    int t = blockIdx.x * 256 + threadIdx.x;   // 0..3071
    int b = t / DD;
    int d = t - b * DD;
    float* p = partial + (size_t)b * NCH * DD + d;
    float v[NCH];
#pragma unroll
    for (int c = 0; c < NCH; ++c) v[c] = p[(size_t)c * DD];
    float run = 0.f;
#pragma unroll
    for (int c = 0; c < NCH; ++c) { float nv = run + v[c]; p[(size_t)c * DD] = run; run = nv; }
}

// Kernel 3: write inclusive cumsum cs[b, s+1, d]; cs[b,0,d] = 0.
// grid (3, NCH, BB), block 256.
__global__ void cumsum_kernel(const float* __restrict__ x, const float* __restrict__ partial,
                              float* __restrict__ cs) {
    int d = blockIdx.x * 256 + threadIdx.x;
    int c = blockIdx.y;
    int b = blockIdx.z;
    float run = partial[(b * NCH + c) * DD + d];
    const float* xp = x + ((size_t)(b * SS) + c * CH) * DD + d;
    float*       cp = cs + ((size_t)(b * (SS + 1)) + c * CH + 1) * DD + d;
    if (c == 0) cs[((size_t)(b * (SS + 1))) * DD + d] = 0.f;
#pragma unroll 4
    for (int i = 0; i < CH; ++i) { run += xp[(size_t)i * DD]; cp[(size_t)i * DD] = run; }
}

// Kernel 4: assemble output rows. grid (NN, BB), block 256, all float4.
// Row layout (f4 indices): mean [0,192) | xs0 [192,384) | pos0 [384,389)
//                          | xs1 [389,581) | pos1 [581,586) | wemb [586,591)
__global__ void gather_kernel(const float* __restrict__ x, const int* __restrict__ spans,
                              const int* __restrict__ pt_labels,
                              const float* __restrict__ wtab, const float* __restrict__ ptab,
                              const float* __restrict__ cs, float* __restrict__ out) {
    int n = blockIdx.x;
    int b = blockIdx.y;
    int t = threadIdx.x;

    int s0 = spans[2 * n];
    int s1 = spans[2 * n + 1];
    int width = s1 - s0 + 1;
    float inv_w = 1.0f / (float)width;

    // em = searchsorted(BUCKET_BINS, width, 'right') - 1; width >= 1 always.
    const int bins[15] = {1, 2, 3, 4, 5, 7, 8, 9, 10, 15, 16, 31, 32, 63, 64};
    int em = 0;
#pragma unroll
    for (int i = 0; i < 15; ++i) em += (width >= bins[i]) ? 1 : 0;

    int l0 = pt_labels[s0];
    int l1 = pt_labels[s1];

    const float4* cs0 = (const float4*)(cs + ((size_t)(b * (SS + 1)) + s0) * DD);
    const float4* cs1 = (const float4*)(cs + ((size_t)(b * (SS + 1)) + s1 + 1) * DD);
    const float4* x0  = (const float4*)(x + ((size_t)(b * SS) + s0) * DD);
    const float4* x1  = (const float4*)(x + ((size_t)(b * SS) + s1) * DD);
    float4* o = (float4*)(out + ((size_t)(b * NN) + n) * ROW);

    if (t < 192) {
        float4 a = cs1[t];
        float4 c0 = cs0[t];
        float4 m;
        m.x = (a.x - c0.x) * inv_w;
        m.y = (a.y - c0.y) * inv_w;
        m.z = (a.z - c0.z) * inv_w;
        m.w = (a.w - c0.w) * inv_w;
        o[t]       = m;
        o[192 + t] = x0[t];
        o[389 + t] = x1[t];
    } else {
        int u = t - 192;
        if (u < 5) {
            o[384 + u] = ((const float4*)(ptab + l0 * PW))[u];
        } else if (u < 10) {
            o[581 + (u - 5)] = ((const float4*)(ptab + l1 * PW))[u - 5];
        } else if (u < 15) {
            o[586 + (u - 10)] = ((const float4*)(wtab + em * PW))[u - 10];
        }
    }
}

extern "C" void kernel_launch(void* const* d_in, const int* in_sizes, int n_in,
                              void* d_out, int out_size, void* d_ws, size_t ws_size,
                              hipStream_t stream) {
    const float* x     = (const float*)d_in[0];
    const int*   spans = (const int*)d_in[1];
    const int*   pt    = (const int*)d_in[2];
    const float* wtab  = (const float*)d_in[3];
    const float* ptab  = (const float*)d_in[4];
    float* out = (float*)d_out;

    float* cs      = (float*)d_ws;                         // BB*(SS+1)*DD floats ~25.2 MB
    float* partial = cs + (size_t)BB * (SS + 1) * DD;      // BB*NCH*DD floats ~0.4 MB

    dim3 g1(3, NCH, BB);
    partial_kernel<<<g1, 256, 0, stream>>>(x, partial);
    prefix_kernel<<<12, 256, 0, stream>>>(partial);
    cumsum_kernel<<<g1, 256, 0, stream>>>(x, partial, cs);
    gather_kernel<<<dim3(NN, BB), 256, 0, stream>>>(x, spans, pt, wtab, ptab, cs, out);
}